// Round 12
// baseline (828.111 us; speedup 1.0000x reference)
//
#include <hip/hip_runtime.h>
#include <hip/hip_cooperative_groups.h>

namespace cg = cooperative_groups;

#define NN 50000
#define D 128
#define EE 600000
#define R 8
#define NR (NN * R)            /* segments, key = dst*R + rel (node-major) */
#define SCAN_CHUNK 1024
#define NSB ((NR + SCAN_CHUNK - 1) / SCAN_CHUNK) /* 391 */
#define KT 36                  /* K tiles: (8*128 + 128)/32 */
#define PGB 1024               /* prep_coop2 grid blocks */

typedef unsigned short u16;
typedef unsigned int u32;
typedef __attribute__((ext_vector_type(8))) short bf16x8;
typedef __attribute__((ext_vector_type(4))) float f32x4;

#define RDL(v_, i_) __builtin_amdgcn_readlane((int)(v_), (i_))

__device__ inline u16 f2bf(float f) {
    union { float f; u32 u; } v; v.f = f;
    return (u16)((v.u + 0x7FFFu + ((v.u >> 16) & 1u)) >> 16);
}

// ---- ONE cooperative prep dispatch (round 12). Round-6's coop failed
// because its 391-block grid starved the streaming phases (VALUBusy 0.6%);
// the scan phases and the coherence pattern were fine. This version keeps
// the verified P1/P2 scan bodies (blocks < NSB) but runs the streaming
// phases grid-strided on a 1024-block grid (4 blocks/CU, 262k threads).
// Replaces 5 dispatches (bprep2, prep2, scanA, scanBC, place2) -> 1 coop
// kernel + 1 memset: prep chain was ~121us of which ~90us was per-dispatch
// overhead/tails (real traffic ~30us). cnt is pre-zeroed via hipMemsetAsync.
__global__ __launch_bounds__(256) void prep_coop2(
        const float4* __restrict__ x, u32* __restrict__ xb,
        const int* __restrict__ src, const int* __restrict__ dst,
        const int* __restrict__ et, int* __restrict__ cnt,
        int* __restrict__ rk, int* __restrict__ off,
        int* __restrict__ bsum, u32* __restrict__ epk,
        const float* __restrict__ w1, const float* __restrict__ root1,
        u16* __restrict__ Bf1,
        const float* __restrict__ w2, const float* __restrict__ root2,
        u16* __restrict__ Bf2) {
    cg::grid_group grid = cg::this_grid();
    __shared__ int ts[256];
    const int b = blockIdx.x, t = threadIdx.x;
    const int gid = b * 256 + t;
    const int GT = PGB * 256;  // 262144

    // ---- P0: xcast ∥ B-frag pack ∥ hist+rank (all independent) ----
    for (int i = gid; i < NN * 32; i += GT) {
        const float4 v = x[i];
        xb[i * 2] = (u32)f2bf(v.x) | ((u32)f2bf(v.y) << 16);
        xb[i * 2 + 1] = (u32)f2bf(v.z) | ((u32)f2bf(v.w) << 16);
    }
    if (gid < 2 * KT * 8 * 64) {  // 36864 pack items, one each
        const int layer = gid / (KT * 8 * 64);
        const int idx = gid - layer * (KT * 8 * 64);
        const float* w = layer ? w2 : w1;
        const float* root = layer ? root2 : root1;
        u16* Bfrag = layer ? Bf2 : Bf1;
        const int lane = idx & 63;
        const int g = (idx >> 6) & 7;
        const int kt = idx >> 9;  // 0..35
        const int col = g * 16 + (lane & 15);
        const int kbase = kt * 32 + (lane >> 4) * 8;
        u16* o = Bfrag + (size_t)idx * 8;
#pragma unroll
        for (int j = 0; j < 8; ++j) {
            const int k = kbase + j;
            float v = (k < R * D)
                          ? w[(size_t)(k >> 7) * (D * D) + (size_t)(k & 127) * D + col]
                          : root[(size_t)(k - R * D) * D + col];
            o[j] = f2bf(v);
        }
    }
    for (int e = gid; e < EE; e += GT)
        rk[e] = atomicAdd(&cnt[dst[e] * R + et[e]], 1);
    __threadfence();
    grid.sync();

    // ---- P1: scanA — block b scans chunk b (r6-verbatim, verified) ----
    if (b < NSB) {
        const int base = b * SCAN_CHUNK + t * 4;
        int v0 = 0, v1 = 0, v2 = 0, v3 = 0;
        if (base + 3 < NR) {
            int4 q = *(const int4*)(cnt + base);
            v0 = q.x; v1 = q.y; v2 = q.z; v3 = q.w;
        } else {
            if (base < NR) v0 = cnt[base];
            if (base + 1 < NR) v1 = cnt[base + 1];
            if (base + 2 < NR) v2 = cnt[base + 2];
        }
        const int s = v0 + v1 + v2 + v3;
        ts[t] = s;
        __syncthreads();
        for (int d = 1; d < 256; d <<= 1) {
            int xx = (t >= d) ? ts[t - d] : 0;
            __syncthreads();
            ts[t] += xx;
            __syncthreads();
        }
        const int excl = ts[t] - s;
        if (base < NR) off[base] = excl;
        if (base + 1 < NR) off[base + 1] = excl + v0;
        if (base + 2 < NR) off[base + 2] = excl + v0 + v1;
        if (base + 3 < NR) off[base + 3] = excl + v0 + v1 + v2;
        if (t == 255) bsum[b] = ts[255];
    }
    __threadfence();
    grid.sync();

    // ---- P2: scanBC — add bsum prefix (r6-verbatim, verified) ----
    if (b < NSB) {
        int p = 0;
        for (int i = t; i < b; i += 256) p += bsum[i];
        __syncthreads();
        ts[t] = p;
        __syncthreads();
        for (int d = 128; d > 0; d >>= 1) {
            if (t < d) ts[t] += ts[t + d];
            __syncthreads();
        }
        const int add = ts[0];
        const int base = b * SCAN_CHUNK + t * 4;
#pragma unroll
        for (int j = 0; j < 4; ++j)
            if (base + j < NR) off[base + j] += add;
        if (b == 0 && t == 0) off[NR] = EE;
    }
    __threadfence();
    grid.sync();

    // ---- P3: place — scatter packed edges, no atomics ----
    for (int e = gid; e < EE; e += GT) {
        const int r = et[e];
        const int p = off[dst[e] * R + r] + rk[e];
        epk[p] = ((u32)src[e] << 3) | (u32)r;
    }
}

// ---- fused RGCN layer (round-5 proven form, 16 dst nodes / block, 8 waves;
// restored verbatim after r6-r11 alternatives all lost to it) ----
// phase 1: per wave ONE contiguous edge stream for its 2 nodes' 16 segments;
//   ALL loads unconditional (clamped addrs, counted vmcnt preserved); scalar
//   (SGPR/readlane) loop state -> s_cbranch only; 3-batch x4 rotation = 12
//   gathers in flight; mean flushed to A-frag LDS slot at scalar boundaries.
// phase 2: A[16x1152] @ B[1152x128]; wave g owns col-tile g; B-frags direct
//   from global (L2-resident). LDS 36.9KB -> 4 blocks/CU, 25k waves.
template <bool OUTBF>
__global__ __launch_bounds__(512, 8) void rgcn_fused(const u32* __restrict__ xb,
                                                     const u16* __restrict__ Bf,
                                                     const int* __restrict__ off,
                                                     const u32* __restrict__ epk,
                                                     const float* __restrict__ bias,
                                                     void* __restrict__ outp) {
    __shared__ u32 A32[KT * 256];  // 36864 B

    const int t = threadIdx.x;
    const int wid = t >> 6;
    const int lane = t & 63;
    const int n0 = blockIdx.x * 16;

    const int q2 = (lane & 15) >> 2;
    const int ktl = lane >> 4;
    const int xv = q2 | ((ktl & 1) << 2);  // swizzle term (3 bits)

    // zero A (empty segments must read 0 in phase 2)
    {
        uint4* Az = (uint4*)A32;
        for (int i = t; i < (KT * 256) / 4; i += 512)
            Az[i] = make_uint4(0, 0, 0, 0);
    }
    __syncthreads();

    const int i0 = wid * 2;        // first of this wave's 2 node slots
    const int nb = n0 + i0;        // always < NN (50000 = 16*3125, no tail)

    // off window: 17 boundaries for 2 nodes, one unconditional clamped load
    int offv;
    {
        int oi = nb * 8 + lane;
        if (oi > NR) oi = NR;      // off[NR] = EE
        offv = off[oi];
    }
    const int e0 = RDL(offv, 0);
    const int e1 = RDL(offv, 16);

    // root rows (independent, issued early)
    const u32 rv0 = xb[(size_t)nb * 64 + lane];
    const u32 rv1 = xb[(size_t)(nb + 1) * 64 + lane];

    // sliding 128-edge epk window in 2 regs (unconditional clamped loads)
    int wb = e0;
    u32 w0, w1;
    {
        int ia = e0 + lane; if (ia >= EE) ia = EE - 1;
        int ib = e0 + 64 + lane; if (ib >= EE) ib = EE - 1;
        w0 = epk[ia];
        w1 = epk[ib];
    }

    // segment state (all scalar)
    int seg = 0;
    while (seg < 16 && RDL(offv, seg + 1) <= e0) ++seg;
    int segEnd = (seg < 16) ? RDL(offv, seg + 1) : 0x7FFFFFFF;
    int segStart = e0;
    float sx = 0.f, sy = 0.f;

#define FLUSH(pp)                                                              \
    do {                                                                       \
        const float inv_ = 1.f / (float)((pp) - segStart);                     \
        const int i_ = i0 + (seg >> 3);                                        \
        const int wb_ = (((i_ ^ xv) + 16 * q2) << 2) + (lane & 3);             \
        A32[((seg & 7) * 4 + ktl) * 256 + wb_] =                               \
            (u32)f2bf(sx * inv_) | ((u32)f2bf(sy * inv_) << 16);               \
        sx = 0.f; sy = 0.f; segStart = (pp);                                   \
        ++seg;                                                                 \
        while (seg < 16 && RDL(offv, seg + 1) <= (pp)) ++seg;                  \
        segEnd = (seg < 16) ? RDL(offv, seg + 1) : 0x7FFFFFFF;                 \
    } while (0)

#define PREF1(d_, pp)                                                          \
    do {                                                                       \
        const int j_ = (pp) - wb;                                              \
        const u32 pk_ = (u32)((j_ < 64) ? RDL(w0, j_) : RDL(w1, j_ - 64));     \
        d_ = xb[(size_t)(pk_ >> 3) * 64 + lane];                               \
    } while (0)

#define PROC1(v_, pp)                                                          \
    do {                                                                       \
        if ((pp) == segEnd) FLUSH(pp);                                         \
        if ((pp) < e1) {                                                       \
            union { u32 u; float f; } lo_, hi_;                                \
            lo_.u = (v_) << 16;                                                \
            hi_.u = (v_) & 0xFFFF0000u;                                        \
            sx += lo_.f;                                                       \
            sy += hi_.f;                                                       \
        }                                                                      \
    } while (0)

    // ---- edge stream: batches of 4, 3 batches in flight ----
    int p = e0;
    u32 a0, a1, a2, a3, b0, b1, b2, b3, c0, c1, c2, c3;
    PREF1(a0, p);     PREF1(a1, p + 1); PREF1(a2, p + 2); PREF1(a3, p + 3);
    PREF1(b0, p + 4); PREF1(b1, p + 5); PREF1(b2, p + 6); PREF1(b3, p + 7);
    const int nbt = (e1 - e0 + 3) >> 2;
#pragma unroll 1
    for (int bt = 0; bt < nbt; ++bt) {
        if (p + 8 - wb >= 64) {  // slide window
            wb += 64; w0 = w1;
            int ia = wb + 64 + lane; if (ia >= EE) ia = EE - 1;
            w1 = epk[ia];
        }
        PREF1(c0, p + 8); PREF1(c1, p + 9); PREF1(c2, p + 10); PREF1(c3, p + 11);
        PROC1(a0, p); PROC1(a1, p + 1); PROC1(a2, p + 2); PROC1(a3, p + 3);
        p += 4;
        a0 = b0; a1 = b1; a2 = b2; a3 = b3;
        b0 = c0; b1 = c1; b2 = c2; b3 = c3;
    }
    if (seg < 16 && segStart < e1) FLUSH(e1);  // final open segment

#undef FLUSH
#undef PREF1
#undef PROC1

    // root section: kt = 32 + ktl
    {
        const int wb0 = (((i0 ^ xv) + 16 * q2) << 2) + (lane & 3);
        const int wb1 = ((((i0 + 1) ^ xv) + 16 * q2) << 2) + (lane & 3);
        A32[(32 + ktl) * 256 + wb0] = rv0;
        A32[(32 + ktl) * 256 + wb1] = rv1;
    }
    __syncthreads();

    // ---- phase 2: wave g -> col-tile g, 36 MFMA ----
    const int g = wid;
    f32x4 acc = {0.f, 0.f, 0.f, 0.f};
    const u16* bp = Bf + ((size_t)g * 64 + lane) * 8;
    const u16* A16 = (const u16*)A32;
#pragma unroll 4
    for (int kt = 0; kt < KT; ++kt) {
        const bf16x8 b = *(const bf16x8*)(bp + (size_t)kt * 4096);
        const int xvr = (lane >> 4) | ((kt & 1) << 2);
        const int lp = (lane ^ xvr) * 8;
        const bf16x8 fa = *(const bf16x8*)(A16 + kt * 512 + lp);
        acc = __builtin_amdgcn_mfma_f32_16x16x32_bf16(fa, b, acc, 0, 0, 0);
    }

    // ---- epilogue: C row=(lane>>4)*4+q, col=g*16+(lane&15); no tail ----
    const int quad = lane >> 4;
    const int l15 = lane & 15;
    const int col = g * 16 + l15;
    const float bb = bias[col];
#pragma unroll
    for (int q = 0; q < 4; ++q) {
        const int row = n0 + quad * 4 + q;
        const float v = fmaxf(acc[q] + bb, 0.f);
        if (OUTBF)
            ((u16*)outp)[(size_t)row * D + col] = f2bf(v);
        else
            ((float*)outp)[(size_t)row * D + col] = v;
    }
}

extern "C" void kernel_launch(void* const* d_in, const int* in_sizes, int n_in,
                              void* d_out, int out_size, void* d_ws, size_t ws_size,
                              hipStream_t stream) {
    const float* x = (const float*)d_in[0];
    const int* ei = (const int*)d_in[1];
    const int* et = (const int*)d_in[2];
    const float* w1 = (const float*)d_in[3];
    const float* root1 = (const float*)d_in[4];
    const float* b1 = (const float*)d_in[5];
    const float* w2 = (const float*)d_in[6];
    const float* root2 = (const float*)d_in[7];
    const float* b2 = (const float*)d_in[8];
    float* out = (float*)d_out;

    char* ws = (char*)d_ws;
    int* off    = (int*)(ws + 0);                  // (NR+1) ints
    int* cnt_i  = (int*)(ws + 1600512);            // NR ints
    int* rk     = (int*)(ws + 3200512);            // EE ints (edge rank)
    int* bsum   = (int*)(ws + 5600512);            // NSB ints
    u32* epk    = (u32*)(ws + 5604096);            // EE u32 (2.4 MB)
    u32* xb     = (u32*)(ws + 8004096);            // N*64 u32 = 12.8 MB
    u32* h      = (u32*)(ws + 20804096);           // N*64 u32 = 12.8 MB
    u16* Bf1    = (u16*)(ws + 33604096);           // 294912 B
    u16* Bf2    = (u16*)(ws + 33899008);           // 294912 B

    const int* srcp = ei;
    const int* dstp = ei + EE;

    // ---- prep: memset cnt, then ONE cooperative kernel ----
    hipMemsetAsync(cnt_i, 0, NR * sizeof(int), stream);
    {
        const float4* xf4 = (const float4*)x;
        u32* xbp = xb;
        const int* sp = srcp;
        const int* dp = dstp;
        const int* ep = et;
        int* cp = cnt_i;
        int* rp = rk;
        int* op = off;
        int* bp = bsum;
        u32* kp = epk;
        const float* w1p = w1; const float* r1p = root1; u16* bf1p = Bf1;
        const float* w2p = w2; const float* r2p = root2; u16* bf2p = Bf2;
        void* cargs[] = {(void*)&xf4, (void*)&xbp, (void*)&sp, (void*)&dp,
                         (void*)&ep, (void*)&cp, (void*)&rp, (void*)&op,
                         (void*)&bp, (void*)&kp, (void*)&w1p, (void*)&r1p,
                         (void*)&bf1p, (void*)&w2p, (void*)&r2p, (void*)&bf2p};
        hipLaunchCooperativeKernel((const void*)prep_coop2, dim3(PGB), dim3(256),
                                   cargs, 0, stream);
    }

    const int fused_blocks = NN / 16;  // 3125, exact

    // layer 1: xb -> h (bf16)
    rgcn_fused<true><<<fused_blocks, 512, 0, stream>>>(xb, Bf1, off, epk, b1,
                                                       (void*)h);
    // layer 2: h -> out (fp32)
    rgcn_fused<false><<<fused_blocks, 512, 0, stream>>>(h, Bf2, off, epk, b2,
                                                        (void*)out);
}

// Round 13
// 287.332 us; speedup vs baseline: 2.8821x; 2.8821x over previous
//
#include <hip/hip_runtime.h>

#define NN 50000
#define D 128
#define EE 600000
#define R 8
#define NR (NN * R)            /* segments, key = dst*R + rel (node-major) */
#define SCAN_CHUNK 1024
#define NSB ((NR + SCAN_CHUNK - 1) / SCAN_CHUNK) /* 391 */
#define KT 36                  /* K tiles: (8*128 + 128)/32 */

typedef unsigned short u16;
typedef unsigned int u32;
typedef __attribute__((ext_vector_type(8))) short bf16x8;
typedef __attribute__((ext_vector_type(4))) float f32x4;

#define RDL(v_, i_) __builtin_amdgcn_readlane((int)(v_), (i_))

__device__ inline u16 f2bf(float f) {
    union { float f; u32 u; } v; v.f = f;
    return (u16)((v.u + 0x7FFFu + ((v.u >> 16) & 1u)) >> 16);
}

template <bool F32> struct LD { using T = u32; };
template <> struct LD<true> { using T = float2; };

// ---- prep pass 1 (round 13): B-frag pack ∥ histogram (fire-and-forget
// atomics, no rank return). xcast is GONE: fused layer 1 reads fp32 x
// directly. cnt (+ scan state) pre-zeroed by one hipMemsetAsync. ----
__global__ __launch_bounds__(256) void prep_hp(const int* __restrict__ dst,
                                               const int* __restrict__ et,
                                               int* __restrict__ cnt,
                                               const float* __restrict__ w1,
                                               const float* __restrict__ root1,
                                               u16* __restrict__ Bf1,
                                               const float* __restrict__ w2,
                                               const float* __restrict__ root2,
                                               u16* __restrict__ Bf2) {
    const int gid = blockIdx.x * 256 + threadIdx.x;
    if (gid < EE) atomicAdd(&cnt[dst[gid] * R + et[gid]], 1);
    if (gid < 2 * KT * 8 * 64) {
        const int layer = gid / (KT * 8 * 64);
        const int idx = gid - layer * (KT * 8 * 64);
        const float* w = layer ? w2 : w1;
        const float* root = layer ? root2 : root1;
        u16* Bfrag = layer ? Bf2 : Bf1;
        const int lane = idx & 63;
        const int g = (idx >> 6) & 7;
        const int kt = idx >> 9;  // 0..35
        const int col = g * 16 + (lane & 15);
        const int kbase = kt * 32 + (lane >> 4) * 8;
        u16* o = Bfrag + (size_t)idx * 8;
#pragma unroll
        for (int j = 0; j < 8; ++j) {
            const int k = kbase + j;
            float v = (k < R * D)
                          ? w[(size_t)(k >> 7) * (D * D) + (size_t)(k & 127) * D + col]
                          : root[(size_t)(k - R * D) * D + col];
            o[j] = f2bf(v);
        }
    }
}

// ---- single-pass exclusive scan with decoupled lookback (round 13):
// replaces scanA+scanBC (one dispatch saved). 391 blocks (co-resident by
// construction -> spin-wait safe). state[b] packs {flag(2b) | value(30b)},
// flag 0=invalid 1=aggregate 2=inclusive-prefix; published via atomicExch
// (value rides in the atomic word itself, no separate fence needed).
// Wave 0 does 64-wide parallel lookback. Writes final off AND cursor. ----
__global__ __launch_bounds__(256) void scan1(const int* __restrict__ cnt,
                                             int* __restrict__ off,
                                             int* __restrict__ cursor,
                                             u32* __restrict__ state) {
    __shared__ int ts[256];
    __shared__ int sbase;
    const int b = blockIdx.x, t = threadIdx.x;
    const int base = b * SCAN_CHUNK + t * 4;
    int v0 = 0, v1 = 0, v2 = 0, v3 = 0;
    if (base + 3 < NR) {
        int4 q = *(const int4*)(cnt + base);
        v0 = q.x; v1 = q.y; v2 = q.z; v3 = q.w;
    } else {
        if (base < NR) v0 = cnt[base];
        if (base + 1 < NR) v1 = cnt[base + 1];
        if (base + 2 < NR) v2 = cnt[base + 2];
    }
    const int s = v0 + v1 + v2 + v3;
    ts[t] = s;
    __syncthreads();
    for (int d = 1; d < 256; d <<= 1) {
        int x = (t >= d) ? ts[t - d] : 0;
        __syncthreads();
        ts[t] += x;
        __syncthreads();
    }
    const int total = ts[255];
    if (t == 0) atomicExch(&state[b], (1u << 30) | (u32)total);
    if (t < 64) {
        int running = 0;
        int wstart = b - 64;               // window [wstart, b-1]
        for (;;) {
            const int idx = wstart + t;
            const u32 sv = (idx >= 0) ? atomicAdd(&state[idx], 0u) : (2u << 30);
            const u32 fl = sv >> 30;
            const unsigned long long binv = __ballot(fl == 0u);
            const unsigned long long bpre = __ballot(fl == 2u);
            if (bpre) {
                const int hp = 63 - __builtin_clzll(bpre);  // rightmost prefix
                if (!(binv & (~0ull << hp))) {
                    int v = (t >= hp) ? (int)(sv & 0x3FFFFFFFu) : 0;
                    for (int o = 32; o; o >>= 1) v += __shfl_xor(v, o);
                    running += v;
                    break;
                }
            } else if (!binv) {            // all aggregates: consume, slide
                int v = (int)(sv & 0x3FFFFFFFu);
                for (int o = 32; o; o >>= 1) v += __shfl_xor(v, o);
                running += v;
                wstart -= 64;
            }
        }
        if (t == 0) {
            sbase = running;
            atomicExch(&state[b], (2u << 30) | (u32)(running + total));
        }
    }
    __syncthreads();
    const int add = sbase;
    const int excl = ts[t] - s + add;
    if (base < NR)     { off[base] = excl;                cursor[base] = excl; }
    if (base + 1 < NR) { off[base + 1] = excl + v0;       cursor[base + 1] = excl + v0; }
    if (base + 2 < NR) { off[base + 2] = excl + v0 + v1;  cursor[base + 2] = excl + v0 + v1; }
    if (base + 3 < NR) { off[base + 3] = excl + v0 + v1 + v2;
                         cursor[base + 3] = excl + v0 + v1 + v2; }
    if (b == 0 && t == 0) off[NR] = EE;
}

// ---- place: returning atomic on cursor gives the slot (round-0-proven) ----
__global__ __launch_bounds__(256) void place_c(const int* __restrict__ src,
                                               const int* __restrict__ dst,
                                               const int* __restrict__ et,
                                               int* __restrict__ cursor,
                                               u32* __restrict__ epk, int E) {
    int e = blockIdx.x * 256 + threadIdx.x;
    if (e < E) {
        const int r = et[e];
        const int p = atomicAdd(&cursor[dst[e] * R + r], 1);
        epk[p] = ((u32)src[e] << 3) | (u32)r;
    }
}

// ---- fused RGCN layer (round-5 proven form; INF32 added round 13) ----
// 16 dst nodes / block, 8 waves. INF32: gather fp32 x directly (float2 per
// lane; PROC is cheaper -- no bf16 unpack), removing the xcast pass + xb
// buffer. Layer 2 reads bf16 h as before.
// phase 1: per wave ONE contiguous edge stream for its 2 nodes' 16 segments;
//   ALL loads unconditional (clamped addrs, counted vmcnt preserved); scalar
//   (SGPR/readlane) loop state -> s_cbranch only; 3-batch x4 rotation = 12
//   gathers in flight; mean flushed to A-frag LDS slot at scalar boundaries.
// phase 2: A[16x1152] @ B[1152x128]; wave g owns col-tile g; B-frags direct
//   from global (L2-resident). LDS 36.9KB -> 4 blocks/CU, 25k waves.
template <bool INF32, bool OUTBF>
__global__ __launch_bounds__(512, 8) void rgcn_fused(const void* __restrict__ xin,
                                                     const u16* __restrict__ Bf,
                                                     const int* __restrict__ off,
                                                     const u32* __restrict__ epk,
                                                     const float* __restrict__ bias,
                                                     void* __restrict__ outp) {
    __shared__ u32 A32[KT * 256];  // 36864 B
    using ldT = typename LD<INF32>::T;

    const float2* xf = (const float2*)xin;
    const u32* xu = (const u32*)xin;

    const int t = threadIdx.x;
    const int wid = t >> 6;
    const int lane = t & 63;
    const int n0 = blockIdx.x * 16;

    const int q2 = (lane & 15) >> 2;
    const int ktl = lane >> 4;
    const int xv = q2 | ((ktl & 1) << 2);  // swizzle term (3 bits)

    // zero A (empty segments must read 0 in phase 2)
    {
        uint4* Az = (uint4*)A32;
        for (int i = t; i < (KT * 256) / 4; i += 512)
            Az[i] = make_uint4(0, 0, 0, 0);
    }
    __syncthreads();

    const int i0 = wid * 2;        // first of this wave's 2 node slots
    const int nb = n0 + i0;        // always < NN (50000 = 16*3125, no tail)

    // off window: 17 boundaries for 2 nodes, one unconditional clamped load
    int offv;
    {
        int oi = nb * 8 + lane;
        if (oi > NR) oi = NR;      // off[NR] = EE
        offv = off[oi];
    }
    const int e0 = RDL(offv, 0);
    const int e1 = RDL(offv, 16);

    // root rows (independent, issued early)
    u32 rv0, rv1;
    if constexpr (INF32) {
        const float2 r0 = xf[(size_t)nb * 64 + lane];
        const float2 r1 = xf[(size_t)(nb + 1) * 64 + lane];
        rv0 = (u32)f2bf(r0.x) | ((u32)f2bf(r0.y) << 16);
        rv1 = (u32)f2bf(r1.x) | ((u32)f2bf(r1.y) << 16);
    } else {
        rv0 = xu[(size_t)nb * 64 + lane];
        rv1 = xu[(size_t)(nb + 1) * 64 + lane];
    }

    // sliding 128-edge epk window in 2 regs (unconditional clamped loads)
    int wb = e0;
    u32 w0, w1;
    {
        int ia = e0 + lane; if (ia >= EE) ia = EE - 1;
        int ib = e0 + 64 + lane; if (ib >= EE) ib = EE - 1;
        w0 = epk[ia];
        w1 = epk[ib];
    }

    // segment state (all scalar)
    int seg = 0;
    while (seg < 16 && RDL(offv, seg + 1) <= e0) ++seg;
    int segEnd = (seg < 16) ? RDL(offv, seg + 1) : 0x7FFFFFFF;
    int segStart = e0;
    float sx = 0.f, sy = 0.f;

#define FLUSH(pp)                                                              \
    do {                                                                       \
        const float inv_ = 1.f / (float)((pp) - segStart);                     \
        const int i_ = i0 + (seg >> 3);                                        \
        const int wb_ = (((i_ ^ xv) + 16 * q2) << 2) + (lane & 3);             \
        A32[((seg & 7) * 4 + ktl) * 256 + wb_] =                               \
            (u32)f2bf(sx * inv_) | ((u32)f2bf(sy * inv_) << 16);               \
        sx = 0.f; sy = 0.f; segStart = (pp);                                   \
        ++seg;                                                                 \
        while (seg < 16 && RDL(offv, seg + 1) <= (pp)) ++seg;                  \
        segEnd = (seg < 16) ? RDL(offv, seg + 1) : 0x7FFFFFFF;                 \
    } while (0)

#define PREF1(d_, pp)                                                          \
    do {                                                                       \
        const int j_ = (pp) - wb;                                              \
        const u32 pk_ = (u32)((j_ < 64) ? RDL(w0, j_) : RDL(w1, j_ - 64));     \
        if constexpr (INF32) d_ = xf[(size_t)(pk_ >> 3) * 64 + lane];          \
        else d_ = xu[(size_t)(pk_ >> 3) * 64 + lane];                          \
    } while (0)

#define PROC1(v_, pp)                                                          \
    do {                                                                       \
        if ((pp) == segEnd) FLUSH(pp);                                         \
        if ((pp) < e1) {                                                       \
            if constexpr (INF32) {                                             \
                sx += (v_).x;                                                  \
                sy += (v_).y;                                                  \
            } else {                                                           \
                union { u32 u; float f; } lo_, hi_;                            \
                lo_.u = ((u32)(v_)) << 16;                                     \
                hi_.u = ((u32)(v_)) & 0xFFFF0000u;                             \
                sx += lo_.f;                                                   \
                sy += hi_.f;                                                   \
            }                                                                  \
        }                                                                      \
    } while (0)

    // ---- edge stream: batches of 4, 3 batches in flight ----
    int p = e0;
    ldT a0, a1, a2, a3, b0, b1, b2, b3, c0, c1, c2, c3;
    PREF1(a0, p);     PREF1(a1, p + 1); PREF1(a2, p + 2); PREF1(a3, p + 3);
    PREF1(b0, p + 4); PREF1(b1, p + 5); PREF1(b2, p + 6); PREF1(b3, p + 7);
    const int nbt = (e1 - e0 + 3) >> 2;
#pragma unroll 1
    for (int bt = 0; bt < nbt; ++bt) {
        if (p + 8 - wb >= 64) {  // slide window
            wb += 64; w0 = w1;
            int ia = wb + 64 + lane; if (ia >= EE) ia = EE - 1;
            w1 = epk[ia];
        }
        PREF1(c0, p + 8); PREF1(c1, p + 9); PREF1(c2, p + 10); PREF1(c3, p + 11);
        PROC1(a0, p); PROC1(a1, p + 1); PROC1(a2, p + 2); PROC1(a3, p + 3);
        p += 4;
        a0 = b0; a1 = b1; a2 = b2; a3 = b3;
        b0 = c0; b1 = c1; b2 = c2; b3 = c3;
    }
    if (seg < 16 && segStart < e1) FLUSH(e1);  // final open segment

#undef FLUSH
#undef PREF1
#undef PROC1

    // root section: kt = 32 + ktl
    {
        const int wb0 = (((i0 ^ xv) + 16 * q2) << 2) + (lane & 3);
        const int wb1 = ((((i0 + 1) ^ xv) + 16 * q2) << 2) + (lane & 3);
        A32[(32 + ktl) * 256 + wb0] = rv0;
        A32[(32 + ktl) * 256 + wb1] = rv1;
    }
    __syncthreads();

    // ---- phase 2: wave g -> col-tile g, 36 MFMA ----
    const int g = wid;
    f32x4 acc = {0.f, 0.f, 0.f, 0.f};
    const u16* bp = Bf + ((size_t)g * 64 + lane) * 8;
    const u16* A16 = (const u16*)A32;
#pragma unroll 4
    for (int kt = 0; kt < KT; ++kt) {
        const bf16x8 b = *(const bf16x8*)(bp + (size_t)kt * 4096);
        const int xvr = (lane >> 4) | ((kt & 1) << 2);
        const int lp = (lane ^ xvr) * 8;
        const bf16x8 fa = *(const bf16x8*)(A16 + kt * 512 + lp);
        acc = __builtin_amdgcn_mfma_f32_16x16x32_bf16(fa, b, acc, 0, 0, 0);
    }

    // ---- epilogue: C row=(lane>>4)*4+q, col=g*16+(lane&15); no tail ----
    const int quad = lane >> 4;
    const int l15 = lane & 15;
    const int col = g * 16 + l15;
    const float bb = bias[col];
#pragma unroll
    for (int q = 0; q < 4; ++q) {
        const int row = n0 + quad * 4 + q;
        const float v = fmaxf(acc[q] + bb, 0.f);
        if (OUTBF)
            ((u16*)outp)[(size_t)row * D + col] = f2bf(v);
        else
            ((float*)outp)[(size_t)row * D + col] = v;
    }
}

extern "C" void kernel_launch(void* const* d_in, const int* in_sizes, int n_in,
                              void* d_out, int out_size, void* d_ws, size_t ws_size,
                              hipStream_t stream) {
    const float* x = (const float*)d_in[0];
    const int* ei = (const int*)d_in[1];
    const int* et = (const int*)d_in[2];
    const float* w1 = (const float*)d_in[3];
    const float* root1 = (const float*)d_in[4];
    const float* b1 = (const float*)d_in[5];
    const float* w2 = (const float*)d_in[6];
    const float* root2 = (const float*)d_in[7];
    const float* b2 = (const float*)d_in[8];
    float* out = (float*)d_out;

    char* ws = (char*)d_ws;
    int* off    = (int*)(ws + 0);                  // (NR+1) ints
    int* cursor = (int*)(ws + 1600512);            // NR ints
    int* cnt_i  = (int*)(ws + 3200512);            // NR ints   (zeroed below)
    u32* state  = (u32*)(ws + 4800512);            // NSB u32s  (zeroed below)
    u32* epk    = (u32*)(ws + 4804096);            // EE u32 (2.4 MB)
    u32* h      = (u32*)(ws + 7204096);            // N*D bf16 = 12.8 MB
    u16* Bf1    = (u16*)(ws + 20004096);           // 294912 B
    u16* Bf2    = (u16*)(ws + 20299008);           // 294912 B

    const int* srcp = ei;
    const int* dstp = ei + EE;

    const int eblocks = (EE + 255) / 256;  // 2344

    // ---- prep: one memset (cnt + scan state, contiguous), pack∥hist,
    // single-pass scan (off+cursor), place ----
    hipMemsetAsync(cnt_i, 0, (size_t)NR * 4 + (size_t)NSB * 4, stream);
    prep_hp<<<eblocks, 256, 0, stream>>>(dstp, et, cnt_i, w1, root1, Bf1,
                                         w2, root2, Bf2);
    scan1<<<NSB, 256, 0, stream>>>(cnt_i, off, cursor, state);
    place_c<<<eblocks, 256, 0, stream>>>(srcp, dstp, et, cursor, epk, EE);

    const int fused_blocks = NN / 16;  // 3125, exact

    // layer 1: x (fp32, direct) -> h (bf16)
    rgcn_fused<true, true><<<fused_blocks, 512, 0, stream>>>(x, Bf1, off, epk,
                                                             b1, (void*)h);
    // layer 2: h -> out (fp32)
    rgcn_fused<false, false><<<fused_blocks, 512, 0, stream>>>(h, Bf2, off, epk,
                                                               b2, (void*)out);
}